// Round 6
// baseline (105.105 us; speedup 1.0000x reference)
//
#include <hip/hip_runtime.h>
#include <hip/hip_bf16.h>

typedef unsigned long long u64;
typedef unsigned short u16;
typedef __attribute__((ext_vector_type(8))) short short8;
typedef __attribute__((ext_vector_type(4))) float float4_t;

#define BB 8
#define SS 512
#define DD 256
#define HH 4
#define TT 20
#define BS (BB*SS)   /* 4096 tokens */

// d_out layout (floats): out[BS*DD], reg[1], Ti[BS], W[BB*HH*SS*SS]
#define REG_OFF (BS*DD)
#define TI_OFF  (REG_OFF+1)
#define W_OFF   (TI_OFF+BS)

static __device__ __forceinline__ u16 f2bf(float f) {
    __hip_bfloat16 h = __float2bfloat16(f);
    return *reinterpret_cast<u16*>(&h);
}

// ===================== Kernel G: gate MLP -> Ti =====================
// 256 blocks x 256 thr; 16 tokens/block. tok = tid>>4, cq = tid&15 (c = cq*2).
__global__ __launch_bounds__(256) void k_gate(
    const float* __restrict__ x,
    const float* __restrict__ Wg1, const float* __restrict__ bg1,
    const float* __restrict__ Wg2, const float* __restrict__ bg2,
    float* __restrict__ ti_out)
{
    __shared__ float wgl[DD*32];   // 32 KB
    __shared__ float xl[16][DD];   // 16 KB
    const int tid  = threadIdx.x;
    const int tok0 = blockIdx.x * 16;

    #pragma unroll
    for (int i = 0; i < 8; ++i) {
        int j = i*256 + tid;   // float4 index
        *reinterpret_cast<float4_t*>(&wgl[j*4]) =
            *reinterpret_cast<const float4_t*>(&Wg1[j*4]);
    }
    #pragma unroll
    for (int m = 0; m < 16; ++m) xl[m][tid] = x[(size_t)(tok0+m)*DD + tid];
    __syncthreads();

    const int tok = tid >> 4;
    const int cq  = tid & 15;
    const int c   = cq * 2;
    float a0 = 0.f, a1 = 0.f;
    #pragma unroll 8
    for (int r = 0; r < DD; ++r) {
        float xv = xl[tok][r];
        a0 += xv * wgl[r*32 + c];
        a1 += xv * wgl[r*32 + c + 1];
    }
    a0 += bg1[c]; a1 += bg1[c+1];
    a0 = a0 > 0.f ? a0 : 0.f;
    a1 = a1 > 0.f ? a1 : 0.f;
    float term = a0 * Wg2[c] + a1 * Wg2[c+1];
    #pragma unroll
    for (int msk = 8; msk >= 1; msk >>= 1) term += __shfl_xor(term, msk, 64);
    if (cq == 0) {
        float g  = term + bg2[0];
        float sg = 1.f / (1.f + expf(-g));
        int ti = (int)ceilf(sg * (float)TT);
        ti = ti < 1 ? 1 : (ti > TT ? TT : ti);
        ti_out[tok0 + tok] = (float)ti;
    }
}

// ===================== Kernel A: one projection + LIF (split-K x token-split) ==========
// grid (256, 3) x 512 thr: bx = 16-token tile, by = projection (0=q,1=k,2=v)
// GEMM: wave w: kh = w>>2 (128 K-rows), tg = w&3 (4 tokens); thread = 4 cols x 4 tokens.
// Waves sharing kh read identical W rows -> L1 reuse.
// LIF: col = tid&255 (h = col>>6, lane), tokhalf = tid>>8 -> 8 tokens each.
__global__ __launch_bounds__(512) void k_proj_lif(
    const float* __restrict__ x, const float* __restrict__ Wq,
    const float* __restrict__ Wk, const float* __restrict__ Wv,
    const float* __restrict__ aq, const float* __restrict__ bq_,
    const float* __restrict__ ak, const float* __restrict__ bk_,
    const float* __restrict__ av, const float* __restrict__ bv_,
    const float* __restrict__ ti_in,
    u64* __restrict__ qpack, u64* __restrict__ kpack,
    u16* __restrict__ vmbT)
{
    __shared__ __align__(16) union {
        float xt[DD][16];       // 16 KB: x transposed (row r, token m)
        float red[2][16][DD];   // 32 KB: per-K-half partial sums
    } sm;
    __shared__ int til[16];
    const int tid  = threadIdx.x;
    const int proj = blockIdx.y;
    const int tok0 = blockIdx.x * 16;

    {
        const int r = tid & 255, mh = tid >> 8;
        #pragma unroll
        for (int i = 0; i < 8; ++i) {
            int m = mh*8 + i;
            sm.xt[r][m] = x[(size_t)(tok0+m)*DD + r];
        }
    }
    if (tid < 16) til[tid] = (int)ti_in[tok0 + tid];
    __syncthreads();

    const float* W    = proj == 0 ? Wq  : (proj == 1 ? Wk  : Wv);
    const float alpha = proj == 0 ? *aq : (proj == 1 ? *ak : *av);
    const float beta  = proj == 0 ? *bq_: (proj == 1 ? *bk_: *bv_);

    const int w  = tid >> 6, l = tid & 63;
    const int kh = w >> 2;          // K-half
    const int tg = w & 3;           // token group

    float4_t a[4];
    #pragma unroll
    for (int i = 0; i < 4; ++i) a[i] = (float4_t){0.f, 0.f, 0.f, 0.f};

    const float* Wp = W + (size_t)(kh*128)*DD + l*4;
    #pragma unroll 4
    for (int r0 = 0; r0 < 128; ++r0) {
        float4_t wf = *reinterpret_cast<const float4_t*>(Wp + (size_t)r0*DD);
        float4_t xv = *reinterpret_cast<const float4_t*>(&sm.xt[kh*128 + r0][tg*4]);
        a[0] += wf*xv.x; a[1] += wf*xv.y; a[2] += wf*xv.z; a[3] += wf*xv.w;
    }
    __syncthreads();   // xt dead
    #pragma unroll
    for (int i = 0; i < 4; ++i)
        *reinterpret_cast<float4_t*>(&sm.red[kh][tg*4 + i][l*4]) = a[i];
    __syncthreads();

    const int col = tid & 255, th = tid >> 8;
    float val[8];
    #pragma unroll
    for (int i = 0; i < 8; ++i) {
        int m = th*8 + i;
        val[i] = sm.red[0][m][col] + sm.red[1][m][col];
    }

    const int lane = tid & 63;
    const int h    = (tid >> 6) & 3;   // = col>>6
    if (proj < 2) {
        u64* pack = (proj == 0) ? qpack : kpack;
        for (int i = 0; i < 8; ++i) {
            const int m  = th*8 + i;
            const int ti = til[m];
            float vv = 0.f, cur = 0.f;
            u64 myw = 0ull;
            #pragma unroll
            for (int t = 0; t < TT; ++t) {
                cur = alpha*cur + val[i];
                vv  = beta*vv + cur;
                bool s = (vv >= 1.f);
                u64 bal = __ballot(s);
                if (s) vv = 0.f;
                if (lane == t && t < ti) myw = bal;
            }
            if (lane < TT)
                pack[((size_t)(tok0+m)*HH + h)*TT + lane] = myw;
        }
    } else {
        u16 tmp[8];
        for (int i = 0; i < 8; ++i) {
            const int m  = th*8 + i;
            const int ti = til[m];
            float vv = 0.f, cur = 0.f, cnt = 0.f;
            #pragma unroll
            for (int t = 0; t < TT; ++t) {
                cur = alpha*cur + val[i];
                vv  = beta*vv + cur;
                bool s = (vv >= 1.f);
                if (s) { vv = 0.f; if (t < ti) cnt += 1.f; }
            }
            tmp[i] = f2bf(cnt * 0.05f);
        }
        // transposed store: vmbT[ch][tok], 8 consecutive tokens = 16B
        *reinterpret_cast<short8*>(&vmbT[(size_t)col*BS + tok0 + th*8]) =
            *reinterpret_cast<short8*>(tmp);
    }
}

// ===================== Kernel C: popcount scores + softmax + W + PV (MFMA) ===========
__global__ __launch_bounds__(256) void k_attn(
    const u64* __restrict__ qpack, const u64* __restrict__ kpack,
    const u16* __restrict__ vmbT,
    float* __restrict__ Wout, float* __restrict__ attn)
{
    __shared__ u64 ql[16][TT];                 // 2.5 KB
    __shared__ __align__(16) u16 CP[16*SS];    // 16 KB: counts, then P (bf16, swizzled)
    const int tid  = threadIdx.x;
    const int tile = blockIdx.x & 31;
    const int h    = (blockIdx.x >> 5) & 3;
    const int b    = blockIdx.x >> 7;
    const int i0   = tile * 16;
    const int lane = tid & 63, wv = tid >> 6;

    for (int idx = tid; idx < 16*TT; idx += 256) {
        int i = idx / TT, t = idx - i*TT;
        ql[i][t] = qpack[((size_t)(b*SS + i0 + i)*HH + h)*TT + t];
    }

    u64 kr0[TT], kr1[TT];
    {
        const u64* kp0 = &kpack[((size_t)(b*SS + tid      )*HH + h)*TT];
        const u64* kp1 = &kpack[((size_t)(b*SS + tid + 256)*HH + h)*TT];
        #pragma unroll
        for (int t = 0; t < TT; ++t) { kr0[t] = kp0[t]; kr1[t] = kp1[t]; }
    }
    __syncthreads();

    // scores as integer counts
    for (int i = 0; i < 16; ++i) {
        int c0 = 0, c1 = 0;
        #pragma unroll
        for (int t = 0; t < TT; ++t) {
            u64 q = ql[i][t];
            c0 += __popcll(q & kr0[t]);
            c1 += __popcll(q & kr1[t]);
        }
        CP[i*SS + tid]       = (u16)c0;
        CP[i*SS + tid + 256] = (u16)c1;
    }
    __syncthreads();

    // softmax per row (wave wv owns rows wv*4..wv*4+3); write W f32, P bf16 swizzled
    for (int rr = 0; rr < 4; ++rr) {
        const int i = wv*4 + rr;
        float sv[8];
        float m = -1e30f;
        #pragma unroll
        for (int k2 = 0; k2 < 8; ++k2) {
            sv[k2] = (float)CP[i*SS + lane + 64*k2] * 0.125f;
            m = fmaxf(m, sv[k2]);
        }
        #pragma unroll
        for (int msk = 32; msk >= 1; msk >>= 1) m = fmaxf(m, __shfl_xor(m, msk, 64));
        float sum = 0.f;
        #pragma unroll
        for (int k2 = 0; k2 < 8; ++k2) { sv[k2] = expf(sv[k2] - m); sum += sv[k2]; }
        #pragma unroll
        for (int msk = 32; msk >= 1; msk >>= 1) sum += __shfl_xor(sum, msk, 64);
        float inv = 1.f / sum;
        size_t wbase = ((size_t)((b*HH + h)*SS) + i0 + i) * SS;
        #pragma unroll
        for (int k2 = 0; k2 < 8; ++k2) {
            int j = lane + 64*k2;
            float wval = sv[k2] * inv;
            Wout[wbase + j] = wval;
            CP[(i*SS + j) ^ ((i & 7) << 3)] = f2bf(wval);
        }
    }
    __syncthreads();

    // PV via mfma_f32_16x16x32_bf16: out tile 16 x 64, wave wv owns n-tile of 16
    const int n0 = wv * 16;
    const int mr = lane & 15;    // A row / B col / D col
    const int g  = lane >> 4;    // k-group
    float4_t acc = {0.f, 0.f, 0.f, 0.f};
    const u16* vbT = vmbT + (size_t)(h*64 + n0 + mr)*BS + b*SS;
    for (int ks = 0; ks < 16; ++ks) {
        int k = ks*32 + g*8;
        int aidx = (mr*SS + k) ^ ((mr & 7) << 3);
        short8 afrag = *reinterpret_cast<const short8*>(&CP[aidx]);
        short8 bfrag = *reinterpret_cast<const short8*>(vbT + k);
        acc = __builtin_amdgcn_mfma_f32_16x16x32_bf16(afrag, bfrag, acc, 0, 0, 0);
    }
    #pragma unroll
    for (int r = 0; r < 4; ++r) {
        int row = g*4 + r;   // D: row=(lane>>4)*4+reg, col=lane&15
        attn[(size_t)(b*SS + i0 + row)*DD + h*64 + n0 + mr] = acc[r];
    }
}

// ===================== Kernel D: out = attn @ Wo + bo (split-K x token-split) + reg =====
__global__ __launch_bounds__(512) void k_outproj(
    const float* __restrict__ attn, const float* __restrict__ Wo,
    const float* __restrict__ bo, const float* __restrict__ ti,
    float* __restrict__ out)
{
    __shared__ __align__(16) union {
        float xt[DD][16];
        float red[2][16][DD];
    } sm;
    __shared__ float ps[8];
    const int tid  = threadIdx.x;
    const int tok0 = blockIdx.x * 16;

    {
        const int r = tid & 255, mh = tid >> 8;
        #pragma unroll
        for (int i = 0; i < 8; ++i) {
            int m = mh*8 + i;
            sm.xt[r][m] = attn[(size_t)(tok0+m)*DD + r];
        }
    }
    __syncthreads();

    const int w  = tid >> 6, l = tid & 63;
    const int kh = w >> 2, tg = w & 3;

    float4_t a[4];
    #pragma unroll
    for (int i = 0; i < 4; ++i) a[i] = (float4_t){0.f, 0.f, 0.f, 0.f};
    const float* Wp = Wo + (size_t)(kh*128)*DD + l*4;
    #pragma unroll 4
    for (int r0 = 0; r0 < 128; ++r0) {
        float4_t wf = *reinterpret_cast<const float4_t*>(Wp + (size_t)r0*DD);
        float4_t xv = *reinterpret_cast<const float4_t*>(&sm.xt[kh*128 + r0][tg*4]);
        a[0] += wf*xv.x; a[1] += wf*xv.y; a[2] += wf*xv.z; a[3] += wf*xv.w;
    }
    __syncthreads();
    #pragma unroll
    for (int i = 0; i < 4; ++i)
        *reinterpret_cast<float4_t*>(&sm.red[kh][tg*4 + i][l*4]) = a[i];
    __syncthreads();

    const int col = tid & 255, th = tid >> 8;
    float bb = bo[col];
    #pragma unroll
    for (int i = 0; i < 8; ++i) {
        int m = th*8 + i;
        float v = sm.red[0][m][col] + sm.red[1][m][col];
        out[(size_t)(tok0+m)*DD + col] = v + bb;
    }

    if (blockIdx.x == 0) {   // fold reg = 1e-3 * mean(Ti)
        float s = 0.f;
        if (tid < 256) for (int m = 0; m < 16; ++m) s += ti[m*256 + tid];
        #pragma unroll
        for (int msk = 32; msk >= 1; msk >>= 1) s += __shfl_xor(s, msk, 64);
        if ((tid & 63) == 0) ps[tid >> 6] = s;
        __syncthreads();
        if (tid == 0) {
            float t = 0.f;
            #pragma unroll
            for (int i = 0; i < 8; ++i) t += ps[i];
            out[REG_OFF] = 1e-3f * t / 4096.f;
        }
    }
}

extern "C" void kernel_launch(void* const* d_in, const int* in_sizes, int n_in,
                              void* d_out, int out_size, void* d_ws, size_t ws_size,
                              hipStream_t stream)
{
    (void)in_sizes; (void)n_in; (void)out_size; (void)ws_size;
    const float* x   = (const float*)d_in[0];
    const float* Wq  = (const float*)d_in[1];
    const float* Wk  = (const float*)d_in[2];
    const float* Wv  = (const float*)d_in[3];
    const float* Wo  = (const float*)d_in[4];
    const float* bo  = (const float*)d_in[5];
    const float* Wg1 = (const float*)d_in[6];
    const float* bg1 = (const float*)d_in[7];
    const float* Wg2 = (const float*)d_in[8];
    const float* bg2 = (const float*)d_in[9];
    const float* aq  = (const float*)d_in[10];
    const float* bq  = (const float*)d_in[11];
    const float* ak  = (const float*)d_in[12];
    const float* bk  = (const float*)d_in[13];
    const float* av  = (const float*)d_in[14];
    const float* bv  = (const float*)d_in[15];
    float* out = (float*)d_out;

    u64* qp = (u64*)d_ws;
    u64* kp = qp + (size_t)BS*HH*TT;
    u16* vmbT = (u16*)(kp + (size_t)BS*HH*TT);
    float* attnbuf = (float*)(vmbT + (size_t)BS*DD);

    k_gate<<<256, 256, 0, stream>>>(x, Wg1, bg1, Wg2, bg2, out + TI_OFF);
    dim3 gproj(256, 3);
    k_proj_lif<<<gproj, 512, 0, stream>>>(x, Wq, Wk, Wv,
        aq, bq, ak, bk, av, bv, out + TI_OFF, qp, kp, vmbT);
    k_attn<<<1024, 256, 0, stream>>>(qp, kp, vmbT, out + W_OFF, attnbuf);
    k_outproj<<<256, 512, 0, stream>>>(attnbuf, Wo, bo, out + TI_OFF, out);
}